// Round 10
// baseline (392.948 us; speedup 1.0000x reference)
//
#include <hip/hip_runtime.h>
#include <math.h>

#define DIM 128
#define HEADS 4
#define NEG 0.2f
#define ELLW 64
#define PBLK 64   // node partitions for the ELL build

typedef unsigned short u16;
typedef unsigned int u32;
typedef short v8s __attribute__((ext_vector_type(8)));
typedef float v4f __attribute__((ext_vector_type(4)));

static __device__ __forceinline__ float lrelu(float x) { return x >= 0.f ? x : NEG * x; }
static __device__ __forceinline__ u16 f2bf(float f) {
    union { float f; u32 u; } v; v.f = f;
    u32 r = v.u + 0x7fffu + ((v.u >> 16) & 1u);
    return (u16)(r >> 16);
}
static __device__ __forceinline__ float bf2f(u16 b) {
    union { u32 u; float f; } v; v.u = ((u32)b) << 16;
    return v.f;
}
static __device__ __forceinline__ void splitbf(float x, u16& hi, u16& lo) {
    hi = f2bf(x);
    lo = f2bf(x - bf2f(hi));
}

// ---------------- ELL build: partition-owned LDS counters, ZERO global atomics ----------------
// blocks 0..PBLK-1: block p owns nodes [p*span, ...); scans ALL edges (L3-resident after
// first touch), claims slots via LDS atomicAdd, plain global stores for ell, writes cnt.
// blocks PBLK..PBLK+1: weight prep; block PBLK+2: z0.
__global__ __launch_bounds__(1024) void k_build(const int* __restrict__ ei, int* __restrict__ cnt,
                                                int* __restrict__ ell,
                                                const float* __restrict__ lin_w,
                                                const float* __restrict__ att_s,
                                                const float* __restrict__ att_d,
                                                u16* __restrict__ WTh, u16* __restrict__ WTl,
                                                float* __restrict__ wv,
                                                const float* __restrict__ emb,
                                                float* __restrict__ z0v,
                                                int E, int N) {
    int b = blockIdx.x;
    if (b < PBLK) {
        __shared__ int lcnt[832];
        int span = (N + PBLK - 1) / PBLK;
        int n0 = b * span;
        int n1 = n0 + span < N ? n0 + span : N;
        int sp = n1 - n0;
        for (int i = threadIdx.x; i < sp; i += blockDim.x) lcnt[i] = 0;
        __syncthreads();
        const int* dst = ei + E;
        int i0 = threadIdx.x * 4;
        int stride = blockDim.x * 4;
        for (; i0 + 3 < E; i0 += stride) {
            int4 d4 = *(const int4*)(dst + i0);
            int dd[4] = {d4.x, d4.y, d4.z, d4.w};
            #pragma unroll
            for (int k = 0; k < 4; k++) {
                int d = dd[k];
                if (d >= n0 && d < n1) {
                    int p = atomicAdd(&lcnt[d - n0], 1);
                    if (p < ELLW) ell[(size_t)d * ELLW + p] = ei[i0 + k];
                }
            }
        }
        for (; i0 < E; i0++) {   // tail (E%4 != 0)
            int d = dst[i0];
            if (d >= n0 && d < n1) {
                int p = atomicAdd(&lcnt[d - n0], 1);
                if (p < ELLW) ell[(size_t)d * ELLW + p] = ei[i0];
            }
        }
        __syncthreads();
        for (int i = threadIdx.x; i < sp; i += blockDim.x) cnt[n0 + i] = lcnt[i];
    } else if (b < PBLK + 2) {
        int l = b - PBLK;                                 // 0,1 -> GAT layers 1,2
        const float* W = lin_w + (size_t)(l + 1) * DIM * DIM;
        for (int i = threadIdx.x; i < DIM * DIM; i += blockDim.x) {
            int k = i >> 7, n = i & 127;
            u16 hi, lo;
            splitbf(W[k * DIM + n], hi, lo);
            WTh[(size_t)l * DIM * DIM + n * DIM + k] = hi;
            WTl[(size_t)l * DIM * DIM + n * DIM + k] = lo;
        }
        for (int i = threadIdx.x; i < DIM * 8; i += blockDim.x) {
            int c = i >> 3, j = i & 7;
            int hh = j & 3;
            const float* att = (j < 4) ? att_s : att_d;
            float s = 0.f;
            for (int d = 0; d < 32; d++)
                s += W[c * DIM + hh * 32 + d] * att[(size_t)(l + 1) * HEADS * 32 + hh * 32 + d];
            wv[(size_t)l * DIM * 8 + c * 8 + j] = s;
        }
    } else {
        int c = threadIdx.x;
        if (c < DIM) {
            float s = 0.f;
            for (int k = 0; k < DIM; k++) s += emb[k] * lin_w[k * DIM + c];
            z0v[c] = s;
        }
    }
}

// ---------------- layer 0 shortcut: h0 split-bf16 + fused layer-1 logits ----------------
__global__ __launch_bounds__(256) void k_hinit(const float* __restrict__ emb,
                                               const float* __restrict__ z0,
                                               const int* __restrict__ cnt,
                                               const float* __restrict__ wv,
                                               u16* __restrict__ hb, u16* __restrict__ hl,
                                               float* __restrict__ a_s, float* __restrict__ a_d,
                                               int N) {
    int tid = threadIdx.x;
    int g = tid & 15;
    int n = blockIdx.x * 16 + (tid >> 4);
    if (n >= N) return;
    float degt = (float)(cnt[n] + 1);   // incl self-loop
    int c0 = 8 * g;
    float4 za = *(const float4*)(z0 + c0);
    float4 zbv = *(const float4*)(z0 + c0 + 4);
    float4 ea = *(const float4*)(emb + c0);
    float4 eb = *(const float4*)(emb + c0 + 4);
    float zr[8] = {za.x, za.y, za.z, za.w, zbv.x, zbv.y, zbv.z, zbv.w};
    float er[8] = {ea.x, ea.y, ea.z, ea.w, eb.x, eb.y, eb.z, eb.w};
    float out[8];
    #pragma unroll
    for (int c = 0; c < 8; c++) {
        float o = zr[c] * (1.f + degt);
        float e = o > 0.f ? o : (__expf(o) - 1.f);
        out[c] = e + er[c];
    }
    size_t base = (size_t)n * DIM + c0;
    u16 hi[8], lo[8];
    #pragma unroll
    for (int c = 0; c < 8; c++) splitbf(out[c], hi[c], lo[c]);
    uint4 hv, lv;
    hv.x = (u32)hi[0] | ((u32)hi[1] << 16); hv.y = (u32)hi[2] | ((u32)hi[3] << 16);
    hv.z = (u32)hi[4] | ((u32)hi[5] << 16); hv.w = (u32)hi[6] | ((u32)hi[7] << 16);
    lv.x = (u32)lo[0] | ((u32)lo[1] << 16); lv.y = (u32)lo[2] | ((u32)lo[3] << 16);
    lv.z = (u32)lo[4] | ((u32)lo[5] << 16); lv.w = (u32)lo[6] | ((u32)lo[7] << 16);
    *(uint4*)(hb + base) = hv;
    *(uint4*)(hl + base) = lv;
    float p[8] = {};
    #pragma unroll
    for (int c = 0; c < 8; c++) {
        const float* w = wv + (c0 + c) * 8;
        #pragma unroll
        for (int j = 0; j < 8; j++) p[j] += out[c] * w[j];
    }
    #pragma unroll
    for (int off = 1; off < 16; off <<= 1)
        #pragma unroll
        for (int j = 0; j < 8; j++) p[j] += __shfl_xor(p[j], off);
    if (g == 0) {
        #pragma unroll
        for (int j = 0; j < 4; j++) {
            a_s[(size_t)n * HEADS + j] = p[j];
            a_d[(size_t)n * HEADS + j] = p[4 + j];
        }
    }
}

// ---------------- split-bf16 MFMA GEMM: z = (hb+hl) @ (Wh+Wl); B-only LDS ----------------
#define LDK 136   // padded row stride in bf16 units

__global__ __launch_bounds__(256) void k_gemm(const u16* __restrict__ hbg,
                                              const u16* __restrict__ hlg,
                                              const u16* __restrict__ WTh,
                                              const u16* __restrict__ WTl,
                                              u16* __restrict__ z, int N) {
    __shared__ u16 Bh[64 * LDK];
    __shared__ u16 Bl[64 * LDK];
    int tid = threadIdx.x;
    int wave = tid >> 6, lane = tid & 63;
    int fr = lane & 15, quad = lane >> 4;
    int row0 = blockIdx.x * 64, col0 = blockIdx.y * 64;
    for (int i = tid; i < 64 * 16; i += 256) {
        int r = i >> 4, seg = i & 15;
        *(uint4*)(Bh + r * LDK + seg * 8) = *(const uint4*)(WTh + (size_t)(col0 + r) * DIM + seg * 8);
        *(uint4*)(Bl + r * LDK + seg * 8) = *(const uint4*)(WTl + (size_t)(col0 + r) * DIM + seg * 8);
    }
    // A fragments straight from global (A-operand layout: m=lane&15, k=quad*8+e per 32-chunk)
    int arow = row0 + wave * 16 + fr;
    v8s ah[4], al[4];
    v8s zero8 = {0, 0, 0, 0, 0, 0, 0, 0};
    if (arow < N) {
        #pragma unroll
        for (int ks = 0; ks < 4; ks++) {
            ah[ks] = *(const v8s*)(hbg + (size_t)arow * DIM + ks * 32 + quad * 8);
            al[ks] = *(const v8s*)(hlg + (size_t)arow * DIM + ks * 32 + quad * 8);
        }
    } else {
        #pragma unroll
        for (int ks = 0; ks < 4; ks++) { ah[ks] = zero8; al[ks] = zero8; }
    }
    __syncthreads();
    v4f acc[4] = {};
    #pragma unroll
    for (int ks = 0; ks < 4; ks++) {
        #pragma unroll
        for (int nn = 0; nn < 4; nn++) {
            v8s bh = *(const v8s*)(Bh + (nn * 16 + fr) * LDK + ks * 32 + quad * 8);
            v8s bl = *(const v8s*)(Bl + (nn * 16 + fr) * LDK + ks * 32 + quad * 8);
            acc[nn] = __builtin_amdgcn_mfma_f32_16x16x32_bf16(ah[ks], bh, acc[nn], 0, 0, 0);
            acc[nn] = __builtin_amdgcn_mfma_f32_16x16x32_bf16(ah[ks], bl, acc[nn], 0, 0, 0);
            acc[nn] = __builtin_amdgcn_mfma_f32_16x16x32_bf16(al[ks], bh, acc[nn], 0, 0, 0);
        }
    }
    // D layout: col=lane&15, row=quad*4+reg
    int rbase = row0 + wave * 16 + quad * 4;
    #pragma unroll
    for (int nn = 0; nn < 4; nn++) {
        int colg = col0 + nn * 16 + fr;
        #pragma unroll
        for (int r = 0; r < 4; r++) {
            int gr = rbase + r;
            if (gr < N) z[(size_t)gr * DIM + colg] = f2bf(acc[nn][r]);
        }
    }
}

// ---------------- single-pass fused aggregation (online softmax, masked 8-wide groups) ----------------
static __device__ __forceinline__ void accw2(uint4 zv, float ex, float msk,
                                             float* acc1, float* acc2) {
    u32 w[4] = {zv.x, zv.y, zv.z, zv.w};
    #pragma unroll
    for (int q = 0; q < 4; q++) {
        union { u32 u; float f; } lo, hi;
        lo.u = w[q] << 16;
        hi.u = w[q] & 0xffff0000u;
        acc1[2 * q] += lo.f * ex;      acc2[2 * q] += lo.f * msk;
        acc1[2 * q + 1] += hi.f * ex;  acc2[2 * q + 1] += hi.f * msk;
    }
}

__global__ __launch_bounds__(256) void k_aggr(const u16* __restrict__ zb,
                                              const float* __restrict__ a_s,
                                              const float* __restrict__ a_d,
                                              const int* __restrict__ cnt,
                                              const int* __restrict__ ell,
                                              u16* __restrict__ hb, u16* __restrict__ hl,
                                              const float* __restrict__ wvn,
                                              float* __restrict__ as_out,
                                              float* __restrict__ ad_out,
                                              float* __restrict__ gbuf,
                                              const int* __restrict__ ptr, int N) {
    __shared__ float arr[16][132];
    __shared__ int gids[16];
    int tid = threadIdx.x;
    int g = tid & 15, node = tid >> 4;
    int n0 = blockIdx.x * 16;
    int n = n0 + node;
    bool active = n < N;
    int hh = g >> 2;
    float out[8];
    if (active) {
        int m = cnt[n];
        if (m > ELLW) m = ELLW;
        const int* row = ell + (size_t)n * ELLW;
        float ad = a_d[(size_t)n * HEADS + hh];
        // online softmax state, seeded by the self-loop (guarantees den >= 1)
        float mx = lrelu(a_s[(size_t)n * HEADS + hh] + ad);
        float den = 1.f;
        float acc1[8] = {}, acc2[8] = {};
        {
            uint4 zv = *(const uint4*)(zb + (size_t)n * DIM + 8 * g);
            accw2(zv, 1.f, 1.f, acc1, acc2);
        }
        int groups = (m + 3) >> 2;
        for (int t = 0; t < groups; t += 2) {
            int jb = t * 4;
            // issue all 8 index loads + 8 a_s gathers + 8 z gathers before dependent math
            int4 sa = *(const int4*)(row + jb);
            int4 sb = *(const int4*)(row + jb + 4);   // ell has slack; masked below
            int idx[8];
            idx[0] = (jb + 0 < m) ? sa.x : n;
            idx[1] = (jb + 1 < m) ? sa.y : n;
            idx[2] = (jb + 2 < m) ? sa.z : n;
            idx[3] = (jb + 3 < m) ? sa.w : n;
            idx[4] = (jb + 4 < m) ? sb.x : n;
            idx[5] = (jb + 5 < m) ? sb.y : n;
            idx[6] = (jb + 6 < m) ? sb.z : n;
            idx[7] = (jb + 7 < m) ? sb.w : n;
            float q[8];
            #pragma unroll
            for (int k = 0; k < 8; k++) q[k] = a_s[(size_t)idx[k] * HEADS + hh];
            uint4 zv[8];
            #pragma unroll
            for (int k = 0; k < 8; k++) zv[k] = *(const uint4*)(zb + (size_t)idx[k] * DIM + 8 * g);
            float l[8];
            #pragma unroll
            for (int k = 0; k < 8; k++)
                l[k] = (jb + k < m) ? lrelu(q[k] + ad) : -1e30f;
            float m8 = l[0];
            #pragma unroll
            for (int k = 1; k < 8; k++) m8 = fmaxf(m8, l[k]);
            if (m8 > mx) {
                float sc = __expf(mx - m8);
                den *= sc;
                #pragma unroll
                for (int c = 0; c < 8; c++) acc1[c] *= sc;
                mx = m8;
            }
            #pragma unroll
            for (int k = 0; k < 8; k++) {
                float ex = __expf(l[k] - mx);     // 0 for masked slots
                float msk = (jb + k < m) ? 1.f : 0.f;
                den += ex;
                accw2(zv[k], ex, msk, acc1, acc2);
            }
        }
        float inv = 1.f / den;
        size_t base = (size_t)n * DIM + 8 * g;
        uint4 hbi = *(const uint4*)(hb + base);
        uint4 hli = *(const uint4*)(hl + base);
        u32 hw[4] = {hbi.x, hbi.y, hbi.z, hbi.w};
        u32 lw[4] = {hli.x, hli.y, hli.z, hli.w};
        #pragma unroll
        for (int q2 = 0; q2 < 4; q2++) {
            float h0 = bf2f((u16)(hw[q2] & 0xffff)) + bf2f((u16)(lw[q2] & 0xffff));
            float h1 = bf2f((u16)(hw[q2] >> 16)) + bf2f((u16)(lw[q2] >> 16));
            float o0 = acc1[2 * q2] * inv + acc2[2 * q2];
            float o1 = acc1[2 * q2 + 1] * inv + acc2[2 * q2 + 1];
            float e0 = o0 > 0.f ? o0 : (__expf(o0) - 1.f);
            float e1 = o1 > 0.f ? o1 : (__expf(o1) - 1.f);
            out[2 * q2] = h0 + e0;
            out[2 * q2 + 1] = h1 + e1;
        }
    } else {
        #pragma unroll
        for (int c = 0; c < 8; c++) out[c] = 0.f;
    }

    if (!gbuf) {
        if (active) {
            size_t base = (size_t)n * DIM + 8 * g;
            u16 chi[8], clo[8];
            #pragma unroll
            for (int c = 0; c < 8; c++) splitbf(out[c], chi[c], clo[c]);
            uint4 hv, lv;
            hv.x = (u32)chi[0] | ((u32)chi[1] << 16); hv.y = (u32)chi[2] | ((u32)chi[3] << 16);
            hv.z = (u32)chi[4] | ((u32)chi[5] << 16); hv.w = (u32)chi[6] | ((u32)chi[7] << 16);
            lv.x = (u32)clo[0] | ((u32)clo[1] << 16); lv.y = (u32)clo[2] | ((u32)clo[3] << 16);
            lv.z = (u32)clo[4] | ((u32)clo[5] << 16); lv.w = (u32)clo[6] | ((u32)clo[7] << 16);
            *(uint4*)(hb + base) = hv;
            *(uint4*)(hl + base) = lv;
            if (wvn) {   // fused next-layer attention logits (exact fp32)
                float p[8] = {};
                int c0 = 8 * g;
                #pragma unroll
                for (int c = 0; c < 8; c++) {
                    const float* w = wvn + (c0 + c) * 8;
                    #pragma unroll
                    for (int jj = 0; jj < 8; jj++) p[jj] += out[c] * w[jj];
                }
                #pragma unroll
                for (int off = 1; off < 16; off <<= 1)
                    #pragma unroll
                    for (int jj = 0; jj < 8; jj++) p[jj] += __shfl_xor(p[jj], off);
                if (g == 0) {
                    #pragma unroll
                    for (int jj = 0; jj < 4; jj++) {
                        as_out[(size_t)n * HEADS + jj] = p[jj];
                        ad_out[(size_t)n * HEADS + jj] = p[4 + jj];
                    }
                }
            }
        }
    } else {
        // fused graph readout: block-local run-length reduction, few atomics
        *(float4*)&arr[node][8 * g] = make_float4(out[0], out[1], out[2], out[3]);
        *(float4*)&arr[node][8 * g + 4] = make_float4(out[4], out[5], out[6], out[7]);
        if (tid < 16) gids[tid] = (n0 + tid < N) ? ptr[n0 + tid] : -1;
        __syncthreads();
        if (tid < 128) {
            int c = tid;
            float acc2 = 0.f;
            int cur = -1;
            #pragma unroll
            for (int i = 0; i < 16; i++) {
                int gid = gids[i];
                if (gid != cur) {
                    if (cur >= 0) atomicAdd(&gbuf[(size_t)cur * DIM + c], acc2);
                    cur = gid;
                    acc2 = 0.f;
                }
                if (gid >= 0) acc2 += arr[i][c];
            }
            if (cur >= 0) atomicAdd(&gbuf[(size_t)cur * DIM + c], acc2);
        }
    }
}

// ---------------- readout phase 2: mean + relu + MLP ----------------
__global__ __launch_bounds__(128) void k_red2(const float* __restrict__ g,
                                              const int* __restrict__ ptr,
                                              const float* __restrict__ w0,
                                              const float* __restrict__ b0,
                                              const float* __restrict__ w1,
                                              const float* __restrict__ b1,
                                              float* __restrict__ y, int N) {
    __shared__ float gsh[DIM];
    int b = blockIdx.x;
    int tid = threadIdx.x;
    int lo = 0, hi = N;
    while (lo < hi) { int m = (lo + hi) >> 1; if (ptr[m] < b) lo = m + 1; else hi = m; }
    int start = lo;
    hi = N;
    while (lo < hi) { int m = (lo + hi) >> 1; if (ptr[m] < b + 1) lo = m + 1; else hi = m; }
    int end = lo;
    float cnt = (float)(end - start);
    float gv = g[(size_t)b * DIM + tid] / fmaxf(cnt, 1.f);
    gsh[tid] = fmaxf(gv, 0.f);
    __syncthreads();
    if (tid < 64) {
        float hj = b0[tid];
        for (int k = 0; k < DIM; k++) hj += gsh[k] * w0[k * 64 + tid];
        hj = fmaxf(hj, 0.f);
        float p = hj * w1[tid];
        #pragma unroll
        for (int off = 32; off > 0; off >>= 1) p += __shfl_down(p, off);
        if (tid == 0) y[b] = p + b1[0];
    }
}

extern "C" void kernel_launch(void* const* d_in, const int* in_sizes, int n_in,
                              void* d_out, int out_size, void* d_ws, size_t ws_size,
                              hipStream_t stream) {
    const int* ei = (const int*)d_in[1];
    const int* ptr = (const int*)d_in[2];
    const float* emb = (const float*)d_in[3];
    const float* lin_w = (const float*)d_in[4];
    const float* att_s = (const float*)d_in[5];
    const float* att_d = (const float*)d_in[6];
    const float* w0 = (const float*)d_in[7];
    const float* b0 = (const float*)d_in[8];
    const float* w1 = (const float*)d_in[9];
    const float* b1 = (const float*)d_in[10];
    float* y = (float*)d_out;

    const int N = in_sizes[0];       // 50000
    const int E = in_sizes[1] / 2;   // 600000
    const int B = out_size;          // 128

    char* wp = (char*)d_ws;
    auto alloc = [&](size_t bytes) {
        void* p = (void*)wp;
        wp += (bytes + 255) & ~(size_t)255;
        return p;
    };
    u16* hb = (u16*)alloc((size_t)N * DIM * 2);
    u16* hl = (u16*)alloc((size_t)N * DIM * 2);
    u16* zb = (u16*)alloc((size_t)N * DIM * 2);
    int* ell = (int*)alloc(((size_t)N * ELLW + 8) * 4);   // +8 ints slack for 8-wide loads
    float* a_s0 = (float*)alloc((size_t)N * HEADS * 4);
    float* a_d0 = (float*)alloc((size_t)N * HEADS * 4);
    float* a_s1 = (float*)alloc((size_t)N * HEADS * 4);
    float* a_d1 = (float*)alloc((size_t)N * HEADS * 4);
    int* cnt = (int*)alloc((size_t)N * 4);                // fully written by k_build
    float* gbuf = (float*)alloc((size_t)B * DIM * 4);     // zero-initialized
    float* z0 = (float*)alloc(DIM * 4);
    u16* WTh = (u16*)alloc((size_t)2 * DIM * DIM * 2);
    u16* WTl = (u16*)alloc((size_t)2 * DIM * DIM * 2);
    float* wv = (float*)alloc((size_t)2 * DIM * 8 * 4);

    hipMemsetAsync(gbuf, 0, (size_t)B * DIM * 4, stream);

    // ELL build (LDS counters, zero global atomics) + weight prep + z0
    k_build<<<PBLK + 3, 1024, 0, stream>>>(ei, cnt, ell, lin_w, att_s, att_d,
                                           WTh, WTl, wv, emb, z0, E, N);
    // layer-0 shortcut (fused layer-1 logits)
    k_hinit<<<(N + 15) / 16, 256, 0, stream>>>(emb, z0, cnt, wv, hb, hl, a_s0, a_d0, N);

    dim3 ggrid((N + 63) / 64, 2);
    int ablocks = (N + 15) / 16;
    // GAT layer 1
    k_gemm<<<ggrid, 256, 0, stream>>>(hb, hl, WTh, WTl, zb, N);
    k_aggr<<<ablocks, 256, 0, stream>>>(zb, a_s0, a_d0, cnt, ell, hb, hl,
                                        wv + (size_t)DIM * 8, a_s1, a_d1,
                                        nullptr, nullptr, N);
    // GAT layer 2 (fused readout)
    k_gemm<<<ggrid, 256, 0, stream>>>(hb, hl, WTh + (size_t)DIM * DIM,
                                      WTl + (size_t)DIM * DIM, zb, N);
    k_aggr<<<ablocks, 256, 0, stream>>>(zb, a_s1, a_d1, cnt, ell, hb, hl,
                                        nullptr, nullptr, nullptr,
                                        gbuf, ptr, N);

    // MLP readout
    k_red2<<<B, 128, 0, stream>>>(gbuf, ptr, w0, b0, w1, b1, y, N);
}

// Round 11
// 265.150 us; speedup vs baseline: 1.4820x; 1.4820x over previous
//
#include <hip/hip_runtime.h>
#include <math.h>

#define DIM 128
#define HEADS 4
#define NEG 0.2f
#define ELLW 64

typedef unsigned short u16;
typedef unsigned int u32;
typedef short v8s __attribute__((ext_vector_type(8)));
typedef float v4f __attribute__((ext_vector_type(4)));

static __device__ __forceinline__ float lrelu(float x) { return x >= 0.f ? x : NEG * x; }
static __device__ __forceinline__ u16 f2bf(float f) {
    union { float f; u32 u; } v; v.f = f;
    u32 r = v.u + 0x7fffu + ((v.u >> 16) & 1u);
    return (u16)(r >> 16);
}
static __device__ __forceinline__ float bf2f(u16 b) {
    union { u32 u; float f; } v; v.u = ((u32)b) << 16;
    return v.f;
}
static __device__ __forceinline__ void splitbf(float x, u16& hi, u16& lo) {
    hi = f2bf(x);
    lo = f2bf(x - bf2f(hi));
}

// ---------------- fused: ELL scatter (line-padded counters) + W2 split + wv + z0 ----------------
// cnt16: one counter per 64B line -> 16x fewer same-line atomic collisions.
__global__ void k_scatter_prep(const int* __restrict__ ei, int* __restrict__ cnt16,
                               int* __restrict__ ell,
                               const float* __restrict__ lin_w, const float* __restrict__ att_s,
                               const float* __restrict__ att_d, u16* __restrict__ WTh,
                               u16* __restrict__ WTl, float* __restrict__ wv,
                               const float* __restrict__ emb, float* __restrict__ z0v,
                               int E, int CB) {
    int b = blockIdx.x;
    if (b < CB) {
        int i = b * blockDim.x + threadIdx.x;
        if (i < E) {
            int s = ei[i], d = ei[E + i];
            int p = atomicAdd(&cnt16[(size_t)d * 16], 1);
            if (p < ELLW) ell[(size_t)d * ELLW + p] = s;
        }
    } else if (b == CB) {
        // split layer-2 weight to bf16 hi/lo (only GEMM left)
        const float* W = lin_w + (size_t)2 * DIM * DIM;
        for (int i = threadIdx.x; i < DIM * DIM; i += blockDim.x) {
            int k = i >> 7, n = i & 127;
            u16 hi, lo;
            splitbf(W[k * DIM + n], hi, lo);
            WTh[n * DIM + k] = hi;
            WTl[n * DIM + k] = lo;
        }
        // wv for both GAT layers: wv[l][c][j] = sum_d W_{l+1}[c, h*32+d] * att[h][d]
        for (int i = threadIdx.x; i < DIM * 8 * 2; i += blockDim.x) {
            int l = i / (DIM * 8);
            int r = i % (DIM * 8);
            int c = r >> 3, j = r & 7;
            int hh = j & 3;
            const float* Wl = lin_w + (size_t)(l + 1) * DIM * DIM;
            const float* att = (j < 4) ? att_s : att_d;
            float s = 0.f;
            for (int d = 0; d < 32; d++)
                s += Wl[c * DIM + hh * 32 + d] * att[(size_t)(l + 1) * HEADS * 32 + hh * 32 + d];
            wv[(size_t)l * DIM * 8 + c * 8 + j] = s;
        }
    } else {
        int c = threadIdx.x;
        if (c < DIM) {
            float s = 0.f;
            for (int k = 0; k < DIM; k++) s += emb[k] * lin_w[k * DIM + c];
            z0v[c] = s;
        }
    }
}

// ---------------- degree tables: h0 / z1-row / layer-1 logits depend only on deg ----------------
// blocks 0..64: table row for deg value d; remaining blocks: compact deg[n] = cnt16[n*16]
__global__ __launch_bounds__(256) void k_tables(const float* __restrict__ z0,
                                                const float* __restrict__ emb,
                                                const float* __restrict__ lin_w,
                                                const float* __restrict__ wv,
                                                const int* __restrict__ cnt16,
                                                int* __restrict__ deg,
                                                float* __restrict__ htab,
                                                float* __restrict__ ztab,
                                                float* __restrict__ atab_s,
                                                float* __restrict__ atab_d, int N) {
    int b = blockIdx.x;
    if (b < 65) {
        __shared__ float h0sh[DIM];
        __shared__ float psh[DIM][8];
        int c = threadIdx.x;
        int d = b;
        if (c < DIM) {
            float degt = (float)(d + 1);                // cnt + self-loop
            float o = z0[c] * (1.f + degt);
            float e = o > 0.f ? o : (__expf(o) - 1.f);
            float h0 = e + emb[c];
            htab[d * DIM + c] = h0;
            h0sh[c] = h0;
            const float* w = wv + c * 8;                // layer-1 wv
            #pragma unroll
            for (int j = 0; j < 8; j++) psh[c][j] = h0 * w[j];
        }
        __syncthreads();
        if (c < 8) {
            float s = 0.f;
            for (int k = 0; k < DIM; k++) s += psh[k][c];
            if (c < 4) atab_s[d * 4 + c] = s;
            else       atab_d[d * 4 + (c - 4)] = s;
        }
        if (c < DIM) {
            const float* W1 = lin_w + (size_t)DIM * DIM;   // GAT layer-1 weight, fp32
            float s = 0.f;
            for (int k = 0; k < DIM; k++) s += h0sh[k] * W1[k * DIM + c];
            ztab[d * DIM + c] = s;                      // fp32-exact z row
        }
    } else {
        int n = (b - 65) * 256 + threadIdx.x;
        if (n < N) deg[n] = cnt16[(size_t)n * 16];
    }
}

// ---------------- layer-1 aggregation: pure table lookups (no GEMM, no hinit) ----------------
__global__ __launch_bounds__(256) void k_aggr1(const int* __restrict__ deg,
                                               const int* __restrict__ ell,
                                               const float* __restrict__ htab,
                                               const float* __restrict__ ztab,
                                               const float* __restrict__ atab_s,
                                               const float* __restrict__ atab_d,
                                               u16* __restrict__ hb, u16* __restrict__ hl,
                                               const float* __restrict__ wvn,
                                               float* __restrict__ as_out,
                                               float* __restrict__ ad_out, int N) {
    int tid = threadIdx.x;
    int g = tid & 15;
    int n = blockIdx.x * 16 + (tid >> 4);
    if (n >= N) return;
    int hh = g >> 2;
    int dn = deg[n];
    int m = dn < ELLW ? dn : ELLW;
    int tn = dn < 64 ? dn : 64;
    const int* row = ell + (size_t)n * ELLW;
    float ad = atab_d[tn * 4 + hh];
    float mx = lrelu(atab_s[tn * 4 + hh] + ad);
    float den = 1.f;
    float acc1[8] = {}, acc2[8] = {};
    {
        const float* zr = ztab + tn * DIM + 8 * g;
        float4 a = *(const float4*)zr, bq = *(const float4*)(zr + 4);
        float zs[8] = {a.x, a.y, a.z, a.w, bq.x, bq.y, bq.z, bq.w};
        #pragma unroll
        for (int c = 0; c < 8; c++) { acc1[c] += zs[c]; acc2[c] += zs[c]; }
    }
    int groups = (m + 3) >> 2;
    for (int t = 0; t < groups; t += 2) {
        int jb = t * 4;
        int4 sa = *(const int4*)(row + jb);
        int4 sb = *(const int4*)(row + jb + 4);
        int idx[8];
        idx[0] = (jb + 0 < m) ? sa.x : n;
        idx[1] = (jb + 1 < m) ? sa.y : n;
        idx[2] = (jb + 2 < m) ? sa.z : n;
        idx[3] = (jb + 3 < m) ? sa.w : n;
        idx[4] = (jb + 4 < m) ? sb.x : n;
        idx[5] = (jb + 5 < m) ? sb.y : n;
        idx[6] = (jb + 6 < m) ? sb.z : n;
        idx[7] = (jb + 7 < m) ? sb.w : n;
        int ts[8];
        #pragma unroll
        for (int k = 0; k < 8; k++) {
            int ds = deg[idx[k]];
            ts[k] = ds < 64 ? ds : 64;
        }
        float l[8];
        #pragma unroll
        for (int k = 0; k < 8; k++)
            l[k] = (jb + k < m) ? lrelu(atab_s[ts[k] * 4 + hh] + ad) : -1e30f;
        float m8 = l[0];
        #pragma unroll
        for (int k = 1; k < 8; k++) m8 = fmaxf(m8, l[k]);
        if (m8 > mx) {
            float sc = __expf(mx - m8);
            den *= sc;
            #pragma unroll
            for (int c = 0; c < 8; c++) acc1[c] *= sc;
            mx = m8;
        }
        #pragma unroll
        for (int half = 0; half < 2; half++) {
            float4 za[4], zq[4];
            #pragma unroll
            for (int k = 0; k < 4; k++) {
                const float* zr = ztab + ts[half * 4 + k] * DIM + 8 * g;
                za[k] = *(const float4*)zr;
                zq[k] = *(const float4*)(zr + 4);
            }
            #pragma unroll
            for (int k = 0; k < 4; k++) {
                int kk = half * 4 + k;
                float ex = __expf(l[kk] - mx);           // 0 for masked slots
                float msk = (jb + kk < m) ? 1.f : 0.f;
                den += ex;
                float zs[8] = {za[k].x, za[k].y, za[k].z, za[k].w,
                               zq[k].x, zq[k].y, zq[k].z, zq[k].w};
                #pragma unroll
                for (int c = 0; c < 8; c++) {
                    acc1[c] += zs[c] * ex;
                    acc2[c] += zs[c] * msk;
                }
            }
        }
    }
    float inv = 1.f / den;
    const float* hr = htab + tn * DIM + 8 * g;
    float4 ha = *(const float4*)hr, hq = *(const float4*)(hr + 4);
    float hv[8] = {ha.x, ha.y, ha.z, ha.w, hq.x, hq.y, hq.z, hq.w};
    float out[8];
    #pragma unroll
    for (int c = 0; c < 8; c++) {
        float o = acc1[c] * inv + acc2[c];
        float e = o > 0.f ? o : (__expf(o) - 1.f);
        out[c] = hv[c] + e;
    }
    size_t base = (size_t)n * DIM + 8 * g;
    u16 chi[8], clo[8];
    #pragma unroll
    for (int c = 0; c < 8; c++) splitbf(out[c], chi[c], clo[c]);
    uint4 hvv, lvv;
    hvv.x = (u32)chi[0] | ((u32)chi[1] << 16); hvv.y = (u32)chi[2] | ((u32)chi[3] << 16);
    hvv.z = (u32)chi[4] | ((u32)chi[5] << 16); hvv.w = (u32)chi[6] | ((u32)chi[7] << 16);
    lvv.x = (u32)clo[0] | ((u32)clo[1] << 16); lvv.y = (u32)clo[2] | ((u32)clo[3] << 16);
    lvv.z = (u32)clo[4] | ((u32)clo[5] << 16); lvv.w = (u32)clo[6] | ((u32)clo[7] << 16);
    *(uint4*)(hb + base) = hvv;
    *(uint4*)(hl + base) = lvv;
    // fused layer-2 attention logits (exact fp32)
    float p[8] = {};
    int c0 = 8 * g;
    #pragma unroll
    for (int c = 0; c < 8; c++) {
        const float* w = wvn + (c0 + c) * 8;
        #pragma unroll
        for (int jj = 0; jj < 8; jj++) p[jj] += out[c] * w[jj];
    }
    #pragma unroll
    for (int off = 1; off < 16; off <<= 1)
        #pragma unroll
        for (int jj = 0; jj < 8; jj++) p[jj] += __shfl_xor(p[jj], off);
    if (g == 0) {
        #pragma unroll
        for (int jj = 0; jj < 4; jj++) {
            as_out[(size_t)n * HEADS + jj] = p[jj];
            ad_out[(size_t)n * HEADS + jj] = p[4 + jj];
        }
    }
}

// ---------------- split-bf16 MFMA GEMM: z = (hb+hl) @ (Wh+Wl); B-only LDS ----------------
#define LDK 136   // padded row stride in bf16 units

__global__ __launch_bounds__(256) void k_gemm(const u16* __restrict__ hbg,
                                              const u16* __restrict__ hlg,
                                              const u16* __restrict__ WTh,
                                              const u16* __restrict__ WTl,
                                              u16* __restrict__ z, int N) {
    __shared__ u16 Bh[64 * LDK];
    __shared__ u16 Bl[64 * LDK];
    int tid = threadIdx.x;
    int wave = tid >> 6, lane = tid & 63;
    int fr = lane & 15, quad = lane >> 4;
    int row0 = blockIdx.x * 64, col0 = blockIdx.y * 64;
    for (int i = tid; i < 64 * 16; i += 256) {
        int r = i >> 4, seg = i & 15;
        *(uint4*)(Bh + r * LDK + seg * 8) = *(const uint4*)(WTh + (size_t)(col0 + r) * DIM + seg * 8);
        *(uint4*)(Bl + r * LDK + seg * 8) = *(const uint4*)(WTl + (size_t)(col0 + r) * DIM + seg * 8);
    }
    int arow = row0 + wave * 16 + fr;
    v8s ah[4], al[4];
    v8s zero8 = {0, 0, 0, 0, 0, 0, 0, 0};
    if (arow < N) {
        #pragma unroll
        for (int ks = 0; ks < 4; ks++) {
            ah[ks] = *(const v8s*)(hbg + (size_t)arow * DIM + ks * 32 + quad * 8);
            al[ks] = *(const v8s*)(hlg + (size_t)arow * DIM + ks * 32 + quad * 8);
        }
    } else {
        #pragma unroll
        for (int ks = 0; ks < 4; ks++) { ah[ks] = zero8; al[ks] = zero8; }
    }
    __syncthreads();
    v4f acc[4] = {};
    #pragma unroll
    for (int ks = 0; ks < 4; ks++) {
        #pragma unroll
        for (int nn = 0; nn < 4; nn++) {
            v8s bh = *(const v8s*)(Bh + (nn * 16 + fr) * LDK + ks * 32 + quad * 8);
            v8s bl = *(const v8s*)(Bl + (nn * 16 + fr) * LDK + ks * 32 + quad * 8);
            acc[nn] = __builtin_amdgcn_mfma_f32_16x16x32_bf16(ah[ks], bh, acc[nn], 0, 0, 0);
            acc[nn] = __builtin_amdgcn_mfma_f32_16x16x32_bf16(ah[ks], bl, acc[nn], 0, 0, 0);
            acc[nn] = __builtin_amdgcn_mfma_f32_16x16x32_bf16(al[ks], bh, acc[nn], 0, 0, 0);
        }
    }
    int rbase = row0 + wave * 16 + quad * 4;
    #pragma unroll
    for (int nn = 0; nn < 4; nn++) {
        int colg = col0 + nn * 16 + fr;
        #pragma unroll
        for (int r = 0; r < 4; r++) {
            int gr = rbase + r;
            if (gr < N) z[(size_t)gr * DIM + colg] = f2bf(acc[nn][r]);
        }
    }
}

// ---------------- layer-2 aggregation (online softmax, masked 8-wide) + fused readout ----------------
static __device__ __forceinline__ void accw2(uint4 zv, float ex, float msk,
                                             float* acc1, float* acc2) {
    u32 w[4] = {zv.x, zv.y, zv.z, zv.w};
    #pragma unroll
    for (int q = 0; q < 4; q++) {
        union { u32 u; float f; } lo, hi;
        lo.u = w[q] << 16;
        hi.u = w[q] & 0xffff0000u;
        acc1[2 * q] += lo.f * ex;      acc2[2 * q] += lo.f * msk;
        acc1[2 * q + 1] += hi.f * ex;  acc2[2 * q + 1] += hi.f * msk;
    }
}

__global__ __launch_bounds__(256) void k_aggr2(const u16* __restrict__ zb,
                                               const float* __restrict__ a_s,
                                               const float* __restrict__ a_d,
                                               const int* __restrict__ deg,
                                               const int* __restrict__ ell,
                                               const u16* __restrict__ hb,
                                               const u16* __restrict__ hl,
                                               float* __restrict__ gbuf,
                                               const int* __restrict__ ptr, int N) {
    __shared__ float arr[16][132];
    __shared__ int gids[16];
    int tid = threadIdx.x;
    int g = tid & 15, node = tid >> 4;
    int n0 = blockIdx.x * 16;
    int n = n0 + node;
    bool active = n < N;
    int hh = g >> 2;
    float out[8];
    if (active) {
        int m = deg[n];
        if (m > ELLW) m = ELLW;
        const int* row = ell + (size_t)n * ELLW;
        float ad = a_d[(size_t)n * HEADS + hh];
        float mx = lrelu(a_s[(size_t)n * HEADS + hh] + ad);
        float den = 1.f;
        float acc1[8] = {}, acc2[8] = {};
        {
            uint4 zv = *(const uint4*)(zb + (size_t)n * DIM + 8 * g);
            accw2(zv, 1.f, 1.f, acc1, acc2);
        }
        int groups = (m + 3) >> 2;
        for (int t = 0; t < groups; t += 2) {
            int jb = t * 4;
            int4 sa = *(const int4*)(row + jb);
            int4 sb = *(const int4*)(row + jb + 4);
            int idx[8];
            idx[0] = (jb + 0 < m) ? sa.x : n;
            idx[1] = (jb + 1 < m) ? sa.y : n;
            idx[2] = (jb + 2 < m) ? sa.z : n;
            idx[3] = (jb + 3 < m) ? sa.w : n;
            idx[4] = (jb + 4 < m) ? sb.x : n;
            idx[5] = (jb + 5 < m) ? sb.y : n;
            idx[6] = (jb + 6 < m) ? sb.z : n;
            idx[7] = (jb + 7 < m) ? sb.w : n;
            float q[8];
            #pragma unroll
            for (int k = 0; k < 8; k++) q[k] = a_s[(size_t)idx[k] * HEADS + hh];
            uint4 zv[8];
            #pragma unroll
            for (int k = 0; k < 8; k++) zv[k] = *(const uint4*)(zb + (size_t)idx[k] * DIM + 8 * g);
            float l[8];
            #pragma unroll
            for (int k = 0; k < 8; k++)
                l[k] = (jb + k < m) ? lrelu(q[k] + ad) : -1e30f;
            float m8 = l[0];
            #pragma unroll
            for (int k = 1; k < 8; k++) m8 = fmaxf(m8, l[k]);
            if (m8 > mx) {
                float sc = __expf(mx - m8);
                den *= sc;
                #pragma unroll
                for (int c = 0; c < 8; c++) acc1[c] *= sc;
                mx = m8;
            }
            #pragma unroll
            for (int k = 0; k < 8; k++) {
                float ex = __expf(l[k] - mx);
                float msk = (jb + k < m) ? 1.f : 0.f;
                den += ex;
                accw2(zv[k], ex, msk, acc1, acc2);
            }
        }
        float inv = 1.f / den;
        size_t base = (size_t)n * DIM + 8 * g;
        uint4 hbi = *(const uint4*)(hb + base);
        uint4 hli = *(const uint4*)(hl + base);
        u32 hw[4] = {hbi.x, hbi.y, hbi.z, hbi.w};
        u32 lw[4] = {hli.x, hli.y, hli.z, hli.w};
        #pragma unroll
        for (int q2 = 0; q2 < 4; q2++) {
            float h0 = bf2f((u16)(hw[q2] & 0xffff)) + bf2f((u16)(lw[q2] & 0xffff));
            float h1 = bf2f((u16)(hw[q2] >> 16)) + bf2f((u16)(lw[q2] >> 16));
            float o0 = acc1[2 * q2] * inv + acc2[2 * q2];
            float o1 = acc1[2 * q2 + 1] * inv + acc2[2 * q2 + 1];
            float e0 = o0 > 0.f ? o0 : (__expf(o0) - 1.f);
            float e1 = o1 > 0.f ? o1 : (__expf(o1) - 1.f);
            out[2 * q2] = h0 + e0;
            out[2 * q2 + 1] = h1 + e1;
        }
    } else {
        #pragma unroll
        for (int c = 0; c < 8; c++) out[c] = 0.f;
    }
    // fused graph readout: block-local run-length reduction, few atomics
    *(float4*)&arr[node][8 * g] = make_float4(out[0], out[1], out[2], out[3]);
    *(float4*)&arr[node][8 * g + 4] = make_float4(out[4], out[5], out[6], out[7]);
    if (tid < 16) gids[tid] = (n0 + tid < N) ? ptr[n0 + tid] : -1;
    __syncthreads();
    if (tid < 128) {
        int c = tid;
        float acc2 = 0.f;
        int cur = -1;
        #pragma unroll
        for (int i = 0; i < 16; i++) {
            int gid = gids[i];
            if (gid != cur) {
                if (cur >= 0) atomicAdd(&gbuf[(size_t)cur * DIM + c], acc2);
                cur = gid;
                acc2 = 0.f;
            }
            if (gid >= 0) acc2 += arr[i][c];
        }
        if (cur >= 0) atomicAdd(&gbuf[(size_t)cur * DIM + c], acc2);
    }
}

// ---------------- readout phase 2: mean + relu + MLP ----------------
__global__ __launch_bounds__(128) void k_red2(const float* __restrict__ g,
                                              const int* __restrict__ ptr,
                                              const float* __restrict__ w0,
                                              const float* __restrict__ b0,
                                              const float* __restrict__ w1,
                                              const float* __restrict__ b1,
                                              float* __restrict__ y, int N) {
    __shared__ float gsh[DIM];
    int b = blockIdx.x;
    int tid = threadIdx.x;
    int lo = 0, hi = N;
    while (lo < hi) { int m = (lo + hi) >> 1; if (ptr[m] < b) lo = m + 1; else hi = m; }
    int start = lo;
    hi = N;
    while (lo < hi) { int m = (lo + hi) >> 1; if (ptr[m] < b + 1) lo = m + 1; else hi = m; }
    int end = lo;
    float cnt = (float)(end - start);
    float gv = g[(size_t)b * DIM + tid] / fmaxf(cnt, 1.f);
    gsh[tid] = fmaxf(gv, 0.f);
    __syncthreads();
    if (tid < 64) {
        float hj = b0[tid];
        for (int k = 0; k < DIM; k++) hj += gsh[k] * w0[k * 64 + tid];
        hj = fmaxf(hj, 0.f);
        float p = hj * w1[tid];
        #pragma unroll
        for (int off = 32; off > 0; off >>= 1) p += __shfl_down(p, off);
        if (tid == 0) y[b] = p + b1[0];
    }
}

extern "C" void kernel_launch(void* const* d_in, const int* in_sizes, int n_in,
                              void* d_out, int out_size, void* d_ws, size_t ws_size,
                              hipStream_t stream) {
    const int* ei = (const int*)d_in[1];
    const int* ptr = (const int*)d_in[2];
    const float* emb = (const float*)d_in[3];
    const float* lin_w = (const float*)d_in[4];
    const float* att_s = (const float*)d_in[5];
    const float* att_d = (const float*)d_in[6];
    const float* w0 = (const float*)d_in[7];
    const float* b0 = (const float*)d_in[8];
    const float* w1 = (const float*)d_in[9];
    const float* b1 = (const float*)d_in[10];
    float* y = (float*)d_out;

    const int N = in_sizes[0];       // 50000
    const int E = in_sizes[1] / 2;   // 600000
    const int B = out_size;          // 128

    char* wp = (char*)d_ws;
    auto alloc = [&](size_t bytes) {
        void* p = (void*)wp;
        wp += (bytes + 255) & ~(size_t)255;
        return p;
    };
    u16* hb = (u16*)alloc((size_t)N * DIM * 2);
    u16* hl = (u16*)alloc((size_t)N * DIM * 2);
    u16* zb = (u16*)alloc((size_t)N * DIM * 2);
    int* ell = (int*)alloc(((size_t)N * ELLW + 8) * 4);
    float* a_s1 = (float*)alloc((size_t)N * HEADS * 4);
    float* a_d1 = (float*)alloc((size_t)N * HEADS * 4);
    int* deg = (int*)alloc((size_t)N * 4);
    // zero-initialized region (one memset): cnt16 (line-padded), gbuf
    int* cnt16 = (int*)alloc((size_t)N * 16 * 4);
    float* gbuf = (float*)alloc((size_t)B * DIM * 4);
    size_t zspan = (size_t)(wp - (char*)cnt16);
    float* z0 = (float*)alloc(DIM * 4);
    u16* WTh = (u16*)alloc((size_t)DIM * DIM * 2);
    u16* WTl = (u16*)alloc((size_t)DIM * DIM * 2);
    float* wv = (float*)alloc((size_t)2 * DIM * 8 * 4);
    float* htab = (float*)alloc((size_t)65 * DIM * 4);
    float* ztab = (float*)alloc((size_t)65 * DIM * 4);
    float* atab_s = (float*)alloc((size_t)65 * 4 * 4);
    float* atab_d = (float*)alloc((size_t)65 * 4 * 4);

    hipMemsetAsync(cnt16, 0, zspan, stream);

    // ELL scatter (padded counters) + layer-2 weight split + wv + z0
    int CB = (E + 255) / 256;
    k_scatter_prep<<<CB + 2, 256, 0, stream>>>(ei, cnt16, ell, lin_w, att_s, att_d,
                                               WTh, WTl, wv, emb, z0, E, CB);
    // degree tables + deg compaction
    int TB = 65 + (N + 255) / 256;
    k_tables<<<TB, 256, 0, stream>>>(z0, emb, lin_w, wv, cnt16, deg,
                                     htab, ztab, atab_s, atab_d, N);
    // GAT layer 1: table-driven aggregation (writes h1 split + layer-2 logits)
    int ablocks = (N + 15) / 16;
    k_aggr1<<<ablocks, 256, 0, stream>>>(deg, ell, htab, ztab, atab_s, atab_d,
                                         hb, hl, wv + (size_t)DIM * 8, a_s1, a_d1, N);
    // GAT layer 2
    dim3 ggrid((N + 63) / 64, 2);
    k_gemm<<<ggrid, 256, 0, stream>>>(hb, hl, WTh, WTl, zb, N);
    k_aggr2<<<ablocks, 256, 0, stream>>>(zb, a_s1, a_d1, deg, ell, hb, hl, gbuf, ptr, N);

    // MLP readout
    k_red2<<<B, 128, 0, stream>>>(gbuf, ptr, w0, b0, w1, b1, y, N);
}

// Round 12
// 247.452 us; speedup vs baseline: 1.5880x; 1.0715x over previous
//
#include <hip/hip_runtime.h>
#include <math.h>

#define DIM 128
#define HEADS 4
#define NEG 0.2f
#define ELLW 64
#define CHE 4096    // edges per phase-A block
#define CAP 4608    // staging slots per bucket (expected 3072, sigma~55 -> 28 sigma margin)

typedef unsigned short u16;
typedef unsigned int u32;
typedef unsigned long long u64;
typedef short v8s __attribute__((ext_vector_type(8)));
typedef float v4f __attribute__((ext_vector_type(4)));

static __device__ __forceinline__ float lrelu(float x) { return x >= 0.f ? x : NEG * x; }
static __device__ __forceinline__ u16 f2bf(float f) {
    union { float f; u32 u; } v; v.f = f;
    u32 r = v.u + 0x7fffu + ((v.u >> 16) & 1u);
    return (u16)(r >> 16);
}
static __device__ __forceinline__ float bf2f(u16 b) {
    union { u32 u; float f; } v; v.u = ((u32)b) << 16;
    return v.f;
}
static __device__ __forceinline__ void splitbf(float x, u16& hi, u16& lo) {
    hi = f2bf(x);
    lo = f2bf(x - bf2f(hi));
}

// ---------------- phase A: bucket edges by dst>>8 (29k atomics) + prep + z0 ----------------
__global__ __launch_bounds__(256) void k_bucket(const int* __restrict__ ei,
                                                int* __restrict__ gcnt,
                                                u64* __restrict__ staging,
                                                const float* __restrict__ lin_w,
                                                const float* __restrict__ att_s,
                                                const float* __restrict__ att_d,
                                                u16* __restrict__ WTh, u16* __restrict__ WTl,
                                                float* __restrict__ wv,
                                                const float* __restrict__ emb,
                                                float* __restrict__ z0v,
                                                int E, int N, int NA) {
    int b = blockIdx.x;
    if (b < NA) {
        __shared__ int hist[256];
        __shared__ int base[256];
        int nbuk = (N + 255) >> 8;
        for (int i = threadIdx.x; i < nbuk; i += 256) hist[i] = 0;
        __syncthreads();
        int e0 = b * CHE;
        int e1 = e0 + CHE < E ? e0 + CHE : E;
        for (int e = e0 + threadIdx.x; e < e1; e += 256)
            atomicAdd(&hist[ei[E + e] >> 8], 1);
        __syncthreads();
        for (int i = threadIdx.x; i < nbuk; i += 256) {
            base[i] = atomicAdd(&gcnt[i], hist[i]);
            hist[i] = 0;
        }
        __syncthreads();
        for (int e = e0 + threadIdx.x; e < e1; e += 256) {
            int s = ei[e], d = ei[E + e];
            int bk = d >> 8;
            int off = atomicAdd(&hist[bk], 1);
            int pos = base[bk] + off;
            if (pos < CAP)
                staging[(size_t)bk * CAP + pos] = ((u64)(u32)d << 32) | (u32)s;
        }
    } else if (b == NA) {
        // split layer-2 weight to bf16 hi/lo (only GEMM left)
        const float* W = lin_w + (size_t)2 * DIM * DIM;
        for (int i = threadIdx.x; i < DIM * DIM; i += blockDim.x) {
            int k = i >> 7, n = i & 127;
            u16 hi, lo;
            splitbf(W[k * DIM + n], hi, lo);
            WTh[n * DIM + k] = hi;
            WTl[n * DIM + k] = lo;
        }
        // wv for both GAT layers
        for (int i = threadIdx.x; i < DIM * 8 * 2; i += blockDim.x) {
            int l = i / (DIM * 8);
            int r = i % (DIM * 8);
            int c = r >> 3, j = r & 7;
            int hh = j & 3;
            const float* Wl = lin_w + (size_t)(l + 1) * DIM * DIM;
            const float* att = (j < 4) ? att_s : att_d;
            float s = 0.f;
            for (int d = 0; d < 32; d++)
                s += Wl[c * DIM + hh * 32 + d] * att[(size_t)(l + 1) * HEADS * 32 + hh * 32 + d];
            wv[(size_t)l * DIM * 8 + c * 8 + j] = s;
        }
    } else {
        int c = threadIdx.x;
        if (c < DIM) {
            float s = 0.f;
            for (int k = 0; k < DIM; k++) s += emb[k] * lin_w[k * DIM + c];
            z0v[c] = s;
        }
    }
}

// ---------------- phase B: per-bucket ELL expansion (LDS counters only) ----------------
__global__ __launch_bounds__(256) void k_expand(const int* __restrict__ gcnt,
                                                const u64* __restrict__ staging,
                                                int* __restrict__ ell, int* __restrict__ deg,
                                                int N) {
    __shared__ int lcnt[256];
    int b = blockIdx.x;
    int n0 = b << 8;
    lcnt[threadIdx.x] = 0;
    __syncthreads();
    int m = gcnt[b];
    if (m > CAP) m = CAP;
    for (int i = threadIdx.x; i < m; i += 256) {
        u64 rec = staging[(size_t)b * CAP + i];
        int d = (int)(rec >> 32);
        int s = (int)(u32)rec;
        int p = atomicAdd(&lcnt[d - n0], 1);
        if (p < ELLW) ell[(size_t)d * ELLW + p] = s;
    }
    __syncthreads();
    int n = n0 + threadIdx.x;
    if (n < N) deg[n] = lcnt[threadIdx.x];
}

// ---------------- degree tables: h0 / z1-row / layer-1 logits depend only on deg ----------------
__global__ __launch_bounds__(256) void k_tables(const float* __restrict__ z0,
                                                const float* __restrict__ emb,
                                                const float* __restrict__ lin_w,
                                                const float* __restrict__ wv,
                                                float* __restrict__ htab,
                                                float* __restrict__ ztab,
                                                float* __restrict__ atab_s,
                                                float* __restrict__ atab_d) {
    __shared__ float h0sh[DIM];
    __shared__ float psh[DIM][8];
    int c = threadIdx.x;
    int d = blockIdx.x;   // 0..64
    if (c < DIM) {
        float degt = (float)(d + 1);                // cnt + self-loop
        float o = z0[c] * (1.f + degt);
        float e = o > 0.f ? o : (__expf(o) - 1.f);
        float h0 = e + emb[c];
        htab[d * DIM + c] = h0;
        h0sh[c] = h0;
        const float* w = wv + c * 8;                // layer-1 wv
        #pragma unroll
        for (int j = 0; j < 8; j++) psh[c][j] = h0 * w[j];
    }
    __syncthreads();
    if (c < 8) {
        float s = 0.f;
        for (int k = 0; k < DIM; k++) s += psh[k][c];
        if (c < 4) atab_s[d * 4 + c] = s;
        else       atab_d[d * 4 + (c - 4)] = s;
    }
    if (c < DIM) {
        const float* W1 = lin_w + (size_t)DIM * DIM;   // GAT layer-1 weight, fp32
        float s = 0.f;
        for (int k = 0; k < DIM; k++) s += h0sh[k] * W1[k * DIM + c];
        ztab[d * DIM + c] = s;                      // fp32-exact z row
    }
}

// ---------------- layer-1 aggregation: pure table lookups (no GEMM, no hinit) ----------------
__global__ __launch_bounds__(256) void k_aggr1(const int* __restrict__ deg,
                                               const int* __restrict__ ell,
                                               const float* __restrict__ htab,
                                               const float* __restrict__ ztab,
                                               const float* __restrict__ atab_s,
                                               const float* __restrict__ atab_d,
                                               u16* __restrict__ hb, u16* __restrict__ hl,
                                               const float* __restrict__ wvn,
                                               float* __restrict__ as_out,
                                               float* __restrict__ ad_out, int N) {
    int tid = threadIdx.x;
    int g = tid & 15;
    int n = blockIdx.x * 16 + (tid >> 4);
    if (n >= N) return;
    int hh = g >> 2;
    int dn = deg[n];
    int m = dn < ELLW ? dn : ELLW;
    int tn = dn < 64 ? dn : 64;
    const int* row = ell + (size_t)n * ELLW;
    float ad = atab_d[tn * 4 + hh];
    float mx = lrelu(atab_s[tn * 4 + hh] + ad);
    float den = 1.f;
    float acc1[8] = {}, acc2[8] = {};
    {
        const float* zr = ztab + tn * DIM + 8 * g;
        float4 a = *(const float4*)zr, bq = *(const float4*)(zr + 4);
        float zs[8] = {a.x, a.y, a.z, a.w, bq.x, bq.y, bq.z, bq.w};
        #pragma unroll
        for (int c = 0; c < 8; c++) { acc1[c] += zs[c]; acc2[c] += zs[c]; }
    }
    int groups = (m + 3) >> 2;
    for (int t = 0; t < groups; t += 2) {
        int jb = t * 4;
        int4 sa = *(const int4*)(row + jb);
        int4 sb = *(const int4*)(row + jb + 4);
        int idx[8];
        idx[0] = (jb + 0 < m) ? sa.x : n;
        idx[1] = (jb + 1 < m) ? sa.y : n;
        idx[2] = (jb + 2 < m) ? sa.z : n;
        idx[3] = (jb + 3 < m) ? sa.w : n;
        idx[4] = (jb + 4 < m) ? sb.x : n;
        idx[5] = (jb + 5 < m) ? sb.y : n;
        idx[6] = (jb + 6 < m) ? sb.z : n;
        idx[7] = (jb + 7 < m) ? sb.w : n;
        int ts[8];
        #pragma unroll
        for (int k = 0; k < 8; k++) {
            int ds = deg[idx[k]];
            ts[k] = ds < 64 ? ds : 64;
        }
        float l[8];
        #pragma unroll
        for (int k = 0; k < 8; k++)
            l[k] = (jb + k < m) ? lrelu(atab_s[ts[k] * 4 + hh] + ad) : -1e30f;
        float m8 = l[0];
        #pragma unroll
        for (int k = 1; k < 8; k++) m8 = fmaxf(m8, l[k]);
        if (m8 > mx) {
            float sc = __expf(mx - m8);
            den *= sc;
            #pragma unroll
            for (int c = 0; c < 8; c++) acc1[c] *= sc;
            mx = m8;
        }
        #pragma unroll
        for (int half = 0; half < 2; half++) {
            float4 za[4], zq[4];
            #pragma unroll
            for (int k = 0; k < 4; k++) {
                const float* zr = ztab + ts[half * 4 + k] * DIM + 8 * g;
                za[k] = *(const float4*)zr;
                zq[k] = *(const float4*)(zr + 4);
            }
            #pragma unroll
            for (int k = 0; k < 4; k++) {
                int kk = half * 4 + k;
                float ex = __expf(l[kk] - mx);           // 0 for masked slots
                float msk = (jb + kk < m) ? 1.f : 0.f;
                den += ex;
                float zs[8] = {za[k].x, za[k].y, za[k].z, za[k].w,
                               zq[k].x, zq[k].y, zq[k].z, zq[k].w};
                #pragma unroll
                for (int c = 0; c < 8; c++) {
                    acc1[c] += zs[c] * ex;
                    acc2[c] += zs[c] * msk;
                }
            }
        }
    }
    float inv = 1.f / den;
    const float* hr = htab + tn * DIM + 8 * g;
    float4 ha = *(const float4*)hr, hq = *(const float4*)(hr + 4);
    float hv[8] = {ha.x, ha.y, ha.z, ha.w, hq.x, hq.y, hq.z, hq.w};
    float out[8];
    #pragma unroll
    for (int c = 0; c < 8; c++) {
        float o = acc1[c] * inv + acc2[c];
        float e = o > 0.f ? o : (__expf(o) - 1.f);
        out[c] = hv[c] + e;
    }
    size_t base = (size_t)n * DIM + 8 * g;
    u16 chi[8], clo[8];
    #pragma unroll
    for (int c = 0; c < 8; c++) splitbf(out[c], chi[c], clo[c]);
    uint4 hvv, lvv;
    hvv.x = (u32)chi[0] | ((u32)chi[1] << 16); hvv.y = (u32)chi[2] | ((u32)chi[3] << 16);
    hvv.z = (u32)chi[4] | ((u32)chi[5] << 16); hvv.w = (u32)chi[6] | ((u32)chi[7] << 16);
    lvv.x = (u32)clo[0] | ((u32)clo[1] << 16); lvv.y = (u32)clo[2] | ((u32)clo[3] << 16);
    lvv.z = (u32)clo[4] | ((u32)clo[5] << 16); lvv.w = (u32)clo[6] | ((u32)clo[7] << 16);
    *(uint4*)(hb + base) = hvv;
    *(uint4*)(hl + base) = lvv;
    // fused layer-2 attention logits (exact fp32)
    float p[8] = {};
    int c0 = 8 * g;
    #pragma unroll
    for (int c = 0; c < 8; c++) {
        const float* w = wvn + (c0 + c) * 8;
        #pragma unroll
        for (int jj = 0; jj < 8; jj++) p[jj] += out[c] * w[jj];
    }
    #pragma unroll
    for (int off = 1; off < 16; off <<= 1)
        #pragma unroll
        for (int jj = 0; jj < 8; jj++) p[jj] += __shfl_xor(p[jj], off);
    if (g == 0) {
        #pragma unroll
        for (int jj = 0; jj < 4; jj++) {
            as_out[(size_t)n * HEADS + jj] = p[jj];
            ad_out[(size_t)n * HEADS + jj] = p[4 + jj];
        }
    }
}

// ---------------- split-bf16 MFMA GEMM: z = (hb+hl) @ (Wh+Wl); B-only LDS ----------------
#define LDK 136   // padded row stride in bf16 units

__global__ __launch_bounds__(256) void k_gemm(const u16* __restrict__ hbg,
                                              const u16* __restrict__ hlg,
                                              const u16* __restrict__ WTh,
                                              const u16* __restrict__ WTl,
                                              u16* __restrict__ z, int N) {
    __shared__ u16 Bh[64 * LDK];
    __shared__ u16 Bl[64 * LDK];
    int tid = threadIdx.x;
    int wave = tid >> 6, lane = tid & 63;
    int fr = lane & 15, quad = lane >> 4;
    int row0 = blockIdx.x * 64, col0 = blockIdx.y * 64;
    for (int i = tid; i < 64 * 16; i += 256) {
        int r = i >> 4, seg = i & 15;
        *(uint4*)(Bh + r * LDK + seg * 8) = *(const uint4*)(WTh + (size_t)(col0 + r) * DIM + seg * 8);
        *(uint4*)(Bl + r * LDK + seg * 8) = *(const uint4*)(WTl + (size_t)(col0 + r) * DIM + seg * 8);
    }
    int arow = row0 + wave * 16 + fr;
    v8s ah[4], al[4];
    v8s zero8 = {0, 0, 0, 0, 0, 0, 0, 0};
    if (arow < N) {
        #pragma unroll
        for (int ks = 0; ks < 4; ks++) {
            ah[ks] = *(const v8s*)(hbg + (size_t)arow * DIM + ks * 32 + quad * 8);
            al[ks] = *(const v8s*)(hlg + (size_t)arow * DIM + ks * 32 + quad * 8);
        }
    } else {
        #pragma unroll
        for (int ks = 0; ks < 4; ks++) { ah[ks] = zero8; al[ks] = zero8; }
    }
    __syncthreads();
    v4f acc[4] = {};
    #pragma unroll
    for (int ks = 0; ks < 4; ks++) {
        #pragma unroll
        for (int nn = 0; nn < 4; nn++) {
            v8s bh = *(const v8s*)(Bh + (nn * 16 + fr) * LDK + ks * 32 + quad * 8);
            v8s bl = *(const v8s*)(Bl + (nn * 16 + fr) * LDK + ks * 32 + quad * 8);
            acc[nn] = __builtin_amdgcn_mfma_f32_16x16x32_bf16(ah[ks], bh, acc[nn], 0, 0, 0);
            acc[nn] = __builtin_amdgcn_mfma_f32_16x16x32_bf16(ah[ks], bl, acc[nn], 0, 0, 0);
            acc[nn] = __builtin_amdgcn_mfma_f32_16x16x32_bf16(al[ks], bh, acc[nn], 0, 0, 0);
        }
    }
    int rbase = row0 + wave * 16 + quad * 4;
    #pragma unroll
    for (int nn = 0; nn < 4; nn++) {
        int colg = col0 + nn * 16 + fr;
        #pragma unroll
        for (int r = 0; r < 4; r++) {
            int gr = rbase + r;
            if (gr < N) z[(size_t)gr * DIM + colg] = f2bf(acc[nn][r]);
        }
    }
}

// ---------------- layer-2 aggregation (online softmax, masked 8-wide) + fused readout ----------------
static __device__ __forceinline__ void accw2(uint4 zv, float ex, float msk,
                                             float* acc1, float* acc2) {
    u32 w[4] = {zv.x, zv.y, zv.z, zv.w};
    #pragma unroll
    for (int q = 0; q < 4; q++) {
        union { u32 u; float f; } lo, hi;
        lo.u = w[q] << 16;
        hi.u = w[q] & 0xffff0000u;
        acc1[2 * q] += lo.f * ex;      acc2[2 * q] += lo.f * msk;
        acc1[2 * q + 1] += hi.f * ex;  acc2[2 * q + 1] += hi.f * msk;
    }
}

__global__ __launch_bounds__(256) void k_aggr2(const u16* __restrict__ zb,
                                               const float* __restrict__ a_s,
                                               const float* __restrict__ a_d,
                                               const int* __restrict__ deg,
                                               const int* __restrict__ ell,
                                               const u16* __restrict__ hb,
                                               const u16* __restrict__ hl,
                                               float* __restrict__ gbuf,
                                               const int* __restrict__ ptr, int N) {
    __shared__ float arr[16][132];
    __shared__ int gids[16];
    int tid = threadIdx.x;
    int g = tid & 15, node = tid >> 4;
    int n0 = blockIdx.x * 16;
    int n = n0 + node;
    bool active = n < N;
    int hh = g >> 2;
    float out[8];
    if (active) {
        int m = deg[n];
        if (m > ELLW) m = ELLW;
        const int* row = ell + (size_t)n * ELLW;
        float ad = a_d[(size_t)n * HEADS + hh];
        float mx = lrelu(a_s[(size_t)n * HEADS + hh] + ad);
        float den = 1.f;
        float acc1[8] = {}, acc2[8] = {};
        {
            uint4 zv = *(const uint4*)(zb + (size_t)n * DIM + 8 * g);
            accw2(zv, 1.f, 1.f, acc1, acc2);
        }
        int groups = (m + 3) >> 2;
        for (int t = 0; t < groups; t += 2) {
            int jb = t * 4;
            int4 sa = *(const int4*)(row + jb);
            int4 sb = *(const int4*)(row + jb + 4);
            int idx[8];
            idx[0] = (jb + 0 < m) ? sa.x : n;
            idx[1] = (jb + 1 < m) ? sa.y : n;
            idx[2] = (jb + 2 < m) ? sa.z : n;
            idx[3] = (jb + 3 < m) ? sa.w : n;
            idx[4] = (jb + 4 < m) ? sb.x : n;
            idx[5] = (jb + 5 < m) ? sb.y : n;
            idx[6] = (jb + 6 < m) ? sb.z : n;
            idx[7] = (jb + 7 < m) ? sb.w : n;
            float q[8];
            #pragma unroll
            for (int k = 0; k < 8; k++) q[k] = a_s[(size_t)idx[k] * HEADS + hh];
            uint4 zv[8];
            #pragma unroll
            for (int k = 0; k < 8; k++) zv[k] = *(const uint4*)(zb + (size_t)idx[k] * DIM + 8 * g);
            float l[8];
            #pragma unroll
            for (int k = 0; k < 8; k++)
                l[k] = (jb + k < m) ? lrelu(q[k] + ad) : -1e30f;
            float m8 = l[0];
            #pragma unroll
            for (int k = 1; k < 8; k++) m8 = fmaxf(m8, l[k]);
            if (m8 > mx) {
                float sc = __expf(mx - m8);
                den *= sc;
                #pragma unroll
                for (int c = 0; c < 8; c++) acc1[c] *= sc;
                mx = m8;
            }
            #pragma unroll
            for (int k = 0; k < 8; k++) {
                float ex = __expf(l[k] - mx);
                float msk = (jb + k < m) ? 1.f : 0.f;
                den += ex;
                accw2(zv[k], ex, msk, acc1, acc2);
            }
        }
        float inv = 1.f / den;
        size_t base = (size_t)n * DIM + 8 * g;
        uint4 hbi = *(const uint4*)(hb + base);
        uint4 hli = *(const uint4*)(hl + base);
        u32 hw[4] = {hbi.x, hbi.y, hbi.z, hbi.w};
        u32 lw[4] = {hli.x, hli.y, hli.z, hli.w};
        #pragma unroll
        for (int q2 = 0; q2 < 4; q2++) {
            float h0 = bf2f((u16)(hw[q2] & 0xffff)) + bf2f((u16)(lw[q2] & 0xffff));
            float h1 = bf2f((u16)(hw[q2] >> 16)) + bf2f((u16)(lw[q2] >> 16));
            float o0 = acc1[2 * q2] * inv + acc2[2 * q2];
            float o1 = acc1[2 * q2 + 1] * inv + acc2[2 * q2 + 1];
            float e0 = o0 > 0.f ? o0 : (__expf(o0) - 1.f);
            float e1 = o1 > 0.f ? o1 : (__expf(o1) - 1.f);
            out[2 * q2] = h0 + e0;
            out[2 * q2 + 1] = h1 + e1;
        }
    } else {
        #pragma unroll
        for (int c = 0; c < 8; c++) out[c] = 0.f;
    }
    // fused graph readout: block-local run-length reduction, few atomics
    *(float4*)&arr[node][8 * g] = make_float4(out[0], out[1], out[2], out[3]);
    *(float4*)&arr[node][8 * g + 4] = make_float4(out[4], out[5], out[6], out[7]);
    if (tid < 16) gids[tid] = (n0 + tid < N) ? ptr[n0 + tid] : -1;
    __syncthreads();
    if (tid < 128) {
        int c = tid;
        float acc2 = 0.f;
        int cur = -1;
        #pragma unroll
        for (int i = 0; i < 16; i++) {
            int gid = gids[i];
            if (gid != cur) {
                if (cur >= 0) atomicAdd(&gbuf[(size_t)cur * DIM + c], acc2);
                cur = gid;
                acc2 = 0.f;
            }
            if (gid >= 0) acc2 += arr[i][c];
        }
        if (cur >= 0) atomicAdd(&gbuf[(size_t)cur * DIM + c], acc2);
    }
}

// ---------------- readout phase 2: mean + relu + MLP ----------------
__global__ __launch_bounds__(128) void k_red2(const float* __restrict__ g,
                                              const int* __restrict__ ptr,
                                              const float* __restrict__ w0,
                                              const float* __restrict__ b0,
                                              const float* __restrict__ w1,
                                              const float* __restrict__ b1,
                                              float* __restrict__ y, int N) {
    __shared__ float gsh[DIM];
    int b = blockIdx.x;
    int tid = threadIdx.x;
    int lo = 0, hi = N;
    while (lo < hi) { int m = (lo + hi) >> 1; if (ptr[m] < b) lo = m + 1; else hi = m; }
    int start = lo;
    hi = N;
    while (lo < hi) { int m = (lo + hi) >> 1; if (ptr[m] < b + 1) lo = m + 1; else hi = m; }
    int end = lo;
    float cnt = (float)(end - start);
    float gv = g[(size_t)b * DIM + tid] / fmaxf(cnt, 1.f);
    gsh[tid] = fmaxf(gv, 0.f);
    __syncthreads();
    if (tid < 64) {
        float hj = b0[tid];
        for (int k = 0; k < DIM; k++) hj += gsh[k] * w0[k * 64 + tid];
        hj = fmaxf(hj, 0.f);
        float p = hj * w1[tid];
        #pragma unroll
        for (int off = 32; off > 0; off >>= 1) p += __shfl_down(p, off);
        if (tid == 0) y[b] = p + b1[0];
    }
}

extern "C" void kernel_launch(void* const* d_in, const int* in_sizes, int n_in,
                              void* d_out, int out_size, void* d_ws, size_t ws_size,
                              hipStream_t stream) {
    const int* ei = (const int*)d_in[1];
    const int* ptr = (const int*)d_in[2];
    const float* emb = (const float*)d_in[3];
    const float* lin_w = (const float*)d_in[4];
    const float* att_s = (const float*)d_in[5];
    const float* att_d = (const float*)d_in[6];
    const float* w0 = (const float*)d_in[7];
    const float* b0 = (const float*)d_in[8];
    const float* w1 = (const float*)d_in[9];
    const float* b1 = (const float*)d_in[10];
    float* y = (float*)d_out;

    const int N = in_sizes[0];       // 50000
    const int E = in_sizes[1] / 2;   // 600000
    const int B = out_size;          // 128
    const int NBUK = (N + 255) >> 8; // 196 dst buckets

    char* wp = (char*)d_ws;
    auto alloc = [&](size_t bytes) {
        void* p = (void*)wp;
        wp += (bytes + 255) & ~(size_t)255;
        return p;
    };
    u16* hb = (u16*)alloc((size_t)N * DIM * 2);
    u16* hl = (u16*)alloc((size_t)N * DIM * 2);
    u16* zb = (u16*)alloc((size_t)N * DIM * 2);
    int* ell = (int*)alloc(((size_t)N * ELLW + 8) * 4);
    u64* staging = (u64*)alloc((size_t)NBUK * CAP * 8);
    float* a_s1 = (float*)alloc((size_t)N * HEADS * 4);
    float* a_d1 = (float*)alloc((size_t)N * HEADS * 4);
    int* deg = (int*)alloc((size_t)N * 4);               // fully written by k_expand
    // zero-initialized region (one memset): gcnt, gbuf
    int* gcnt = (int*)alloc((size_t)NBUK * 4);
    float* gbuf = (float*)alloc((size_t)B * DIM * 4);
    size_t zspan = (size_t)(wp - (char*)gcnt);
    float* z0 = (float*)alloc(DIM * 4);
    u16* WTh = (u16*)alloc((size_t)DIM * DIM * 2);
    u16* WTl = (u16*)alloc((size_t)DIM * DIM * 2);
    float* wv = (float*)alloc((size_t)2 * DIM * 8 * 4);
    float* htab = (float*)alloc((size_t)65 * DIM * 4);
    float* ztab = (float*)alloc((size_t)65 * DIM * 4);
    float* atab_s = (float*)alloc((size_t)65 * 4 * 4);
    float* atab_d = (float*)alloc((size_t)65 * 4 * 4);

    hipMemsetAsync(gcnt, 0, zspan, stream);

    // phase A: bucket edges by dst>>8 (~29k atomics) + prep + z0
    int NA = (E + CHE - 1) / CHE;
    k_bucket<<<NA + 2, 256, 0, stream>>>(ei, gcnt, staging, lin_w, att_s, att_d,
                                         WTh, WTl, wv, emb, z0, E, N, NA);
    // phase B: per-bucket ELL expansion (LDS counters, writes deg)
    k_expand<<<NBUK, 256, 0, stream>>>(gcnt, staging, ell, deg, N);
    // degree tables
    k_tables<<<65, 256, 0, stream>>>(z0, emb, lin_w, wv, htab, ztab, atab_s, atab_d);
    // GAT layer 1: table-driven aggregation (writes h1 split + layer-2 logits)
    int ablocks = (N + 15) / 16;
    k_aggr1<<<ablocks, 256, 0, stream>>>(deg, ell, htab, ztab, atab_s, atab_d,
                                         hb, hl, wv + (size_t)DIM * 8, a_s1, a_d1, N);
    // GAT layer 2
    dim3 ggrid((N + 63) / 64, 2);
    k_gemm<<<ggrid, 256, 0, stream>>>(hb, hl, WTh, WTl, zb, N);
    k_aggr2<<<ablocks, 256, 0, stream>>>(zb, a_s1, a_d1, deg, ell, hb, hl, gbuf, ptr, N);

    // MLP readout
    k_red2<<<B, 128, 0, stream>>>(gbuf, ptr, w0, b0, w1, b1, y, N);
}